// Round 10
// baseline (131.536 us; speedup 1.0000x reference)
//
#include <hip/hip_runtime.h>

// ---------------------------------------------------------------------------
// SocialPooling: pooled = per-person 8x8-grid scatter-add of neighbor hiddens,
// out = relu(pooled @ W + b).  M=B=4096, K=4096, N=1024.
// R10: R9 + K-phase stagger in GEMM: co-resident blocks (b, b+256) start the
// K-loop half a rotation apart so their staging bursts / barrier drains
// interleave instead of colliding.  Everything else is the proven R4/R9
// structure (128x64 tile, BK=128, 2-barrier loop, 256B/16-slot XOR swizzle,
// 32x32x16 MFMA, XCD m-cluster, grid 512 = 2 blocks/CU).
// ---------------------------------------------------------------------------

#define BM 128
#define BN 64
#define BK 128   // shorts (bf16) per K-block

typedef short short8 __attribute__((ext_vector_type(8)));
typedef short short4v __attribute__((ext_vector_type(4)));
typedef float floatx16 __attribute__((ext_vector_type(16)));

__device__ inline short f2bf(float x) {
    union { float f; unsigned u; } v; v.f = x;
    unsigned r = v.u + 0x7fffu + ((v.u >> 16) & 1u);   // round-to-nearest-even
    return (short)(r >> 16);
}

__device__ inline void gload_lds16(const void* g, void* l) {
    __builtin_amdgcn_global_load_lds(
        (const __attribute__((address_space(1))) void*)g,
        (__attribute__((address_space(3))) void*)l,
        16, 0, 0);
}

// ---------------------------------------------------------------------------
// Kernel 1: prep = pool (blocks 0..1023) + W transpose/cast (blocks 1024..2047)
// merged so the two independent stages run concurrently.  (R9-proven.)
// ---------------------------------------------------------------------------
__global__ __launch_bounds__(256) void prep_kernel(
    const float* __restrict__ h,     // (B, 64)
    const float* __restrict__ pos,   // (B, 2)
    short* __restrict__ pooled,      // (B, 4096) bf16
    const float* __restrict__ W,     // (K, N)
    short* __restrict__ Wt,          // (N, K) bf16
    int K, int N, int poolBlocks)
{
    __shared__ __align__(16) unsigned char sh[18944];
    const int tid = threadIdx.x;

    if ((int)blockIdx.x < poolBlocks) {
        // ----- pooling: 4 persons of one sequence per block -----
        float* hs = (float*)sh;                          // 64*64 f32 = 16 KB
        float* px = (float*)(sh + 16384);
        float* py = (float*)(sh + 16640);
        unsigned long long* wmask = (unsigned long long*)(sh + 16896); // 4*64

        const int lane = tid & 63;
        const int w    = tid >> 6;
        const int s    = blockIdx.x >> 4;
        const int grp  = blockIdx.x & 15;
        const size_t base = (size_t)s * 64;

        const float4* hv  = (const float4*)(h + base * 64);
        float4*       hsv = (float4*)hs;
        #pragma unroll
        for (int c = 0; c < 4; ++c) hsv[tid + c * 256] = hv[tid + c * 256];
        if (tid < 64) {
            float2 p = ((const float2*)pos)[base + tid];
            px[tid] = p.x; py[tid] = p.y;
        }
        wmask[w * 64 + lane] = 0ull;
        __syncthreads();

        const int i = grp * 4 + w;
        const float tlx = px[i] - 1.0f;
        const float tly = py[i] + 1.0f;
        const float brx = px[i] + 1.0f;
        const float bry = py[i] - 1.0f;

        {   // lane j: neighbor j's cell for person i (wave-local)
            const int j = lane;
            const float ox = px[j], oy = py[j];
            if (ox < brx && ox > tlx && oy < tly && oy > bry && j != i) {
                int cx = (int)floorf((ox - tlx) * 4.0f);
                int cy = (int)floorf((tly - oy) * 4.0f);
                atomicOr(&wmask[w * 64 + cx + cy * 8], 1ull << j);
            }
        }

        // phase C: 2 cells per wave-pass; lane half picks the cell, each lane
        // sums a float2 dim-pair.  (R9-proven.)
        const int half = lane >> 5;            // cell offset 0/1
        const int d0   = (lane & 31) * 2;      // dim pair
        const size_t orow = (base + i) * 4096;
        unsigned short* pooledU = (unsigned short*)pooled;
        for (int c = 0; c < 64; c += 2) {
            unsigned long long m = wmask[w * 64 + c + half];
            float ax = 0.f, ay = 0.f;
            while (m) {
                int j0 = __builtin_ctzll(m); m &= m - 1;
                float2 hv2 = *(const float2*)&hs[j0 * 64 + d0];
                ax += hv2.x; ay += hv2.y;
            }
            unsigned pk = ((unsigned)(unsigned short)f2bf(ay) << 16)
                        |  (unsigned short)f2bf(ax);
            *(unsigned*)&pooledU[orow + (size_t)(c + half) * 64 + d0] = pk;
        }
    } else {
        // ----- W (K x N f32) -> Wt (N x K bf16), 64x64 tiles -----
        float* t = (float*)sh;                 // [64][65]
        const int bid = blockIdx.x - poolBlocks;
        const int k0 = (bid & 63) * 64;
        const int n0 = (bid >> 6) * 64;

        const int r  = tid >> 4;               // 0..15
        const int cq = (tid & 15) * 4;
        #pragma unroll
        for (int i2 = 0; i2 < 4; ++i2) {
            const int row = r + i2 * 16;
            float4 v = *(const float4*)&W[(size_t)(k0 + row) * N + n0 + cq];
            t[row * 65 + cq + 0] = v.x; t[row * 65 + cq + 1] = v.y;
            t[row * 65 + cq + 2] = v.z; t[row * 65 + cq + 3] = v.w;
        }
        __syncthreads();
        const int nl = tid >> 4;
        const int kq = (tid & 15) * 4;
        #pragma unroll
        for (int i2 = 0; i2 < 4; ++i2) {
            const int n = nl + i2 * 16;
            short4v o;
            o.x = f2bf(t[(kq + 0) * 65 + n]); o.y = f2bf(t[(kq + 1) * 65 + n]);
            o.z = f2bf(t[(kq + 2) * 65 + n]); o.w = f2bf(t[(kq + 3) * 65 + n]);
            *(short4v*)&Wt[(size_t)(n0 + n) * K + k0 + kq] = o;
        }
    }
}

// ---------------------------------------------------------------------------
// Kernel 2 (R4 structure + K-stagger): C = relu(A @ Bt^T + bias).
// 128x64 block tile, BK=128, 4 waves (2x2), wave tile 64x32 = 2x1 of 32x32x16
// MFMA.  global_load_lds(16B) staging with XOR granule swizzle (0 conflicts
// measured).  XCD m-clustered mapping.  Blocks b and b+256 (co-resident on a
// CU) start the K-loop K/2 apart to de-collide staging bursts/drains.
// ---------------------------------------------------------------------------
__global__ __launch_bounds__(256) void gemm_bias_relu(
    const short* __restrict__ A,
    const short* __restrict__ Bt,
    const float* __restrict__ bias,
    float* __restrict__ out,
    int M, int N, int K)
{
    __shared__ __align__(16) short As[BM * BK];  // 32 KB
    __shared__ __align__(16) short Bs[BN * BK];  // 16 KB

    const int tid  = threadIdx.x;
    const int lane = tid & 63;
    const int wave = tid >> 6;
    const int wr = wave >> 1;          // wave row (m): 0..1
    const int wc = wave & 1;           // wave col (n): 0..1
    const int nl = lane & 31;          // MFMA row/col within 32
    const int hl = lane >> 5;          // K-half
    const int ml = lane & 15;          // swizzle key (= row&15)

    // XCD m-clustered mapping (dispatch: block b -> XCD b%8)
    const int b  = blockIdx.x;
    const int ib = b >> 3;
    const int m0 = ((b & 7) * 4 + (ib >> 4)) * BM;
    const int n0 = (ib & 15) * BN;

    // K-phase stagger: blocks {0..255} start at 0, {256..511} at K/2.
    const int kb0 = ((ib >> 5) & 1) * (K >> 1);

    const int r4   = lane >> 4;        // row within 4-row staging group
    const int slot = lane & 15;        // 16B-granule slot within 256B row

    const short* ag[8];
    const short* bg[4];
    #pragma unroll
    for (int c = 0; c < 8; ++c) {
        const int gi = c * 4 + wave;           // 0..31
        const int rl = gi * 4 + r4;            // 0..127
        ag[c] = A + (size_t)(m0 + rl) * K + (slot ^ (rl & 15)) * 8;
    }
    #pragma unroll
    for (int c = 0; c < 4; ++c) {
        const int gi = c * 4 + wave;           // 0..15
        const int rl = gi * 4 + r4;            // 0..63
        bg[c] = Bt + (size_t)(n0 + rl) * K + (slot ^ (rl & 15)) * 8;
    }

    floatx16 acc[2];
    #pragma unroll
    for (int mt = 0; mt < 2; ++mt)
        #pragma unroll
        for (int r = 0; r < 16; ++r) acc[mt][r] = 0.f;

    for (int i = 0; i < K; i += BK) {
        const int kb = (kb0 + i) & (K - 1);    // rotated K-block (uniform)
        if (i) __syncthreads();
        #pragma unroll
        for (int c = 0; c < 8; ++c)
            gload_lds16(ag[c] + kb, &As[(c * 4 + wave) * 512]);
        #pragma unroll
        for (int c = 0; c < 4; ++c)
            gload_lds16(bg[c] + kb, &Bs[(c * 4 + wave) * 512]);
        __syncthreads();

        #pragma unroll
        for (int t = 0; t < 8; ++t) {                  // 8 x K=16 steps
            const int g  = 2 * t + hl;                 // needed granule
            short8 a0 = *(const short8*)&As[(wr * 64 +      nl) * BK + ((g ^ ml) * 8)];
            short8 a1 = *(const short8*)&As[(wr * 64 + 32 + nl) * BK + ((g ^ ml) * 8)];
            short8 bfr = *(const short8*)&Bs[(wc * 32 +     nl) * BK + ((g ^ ml) * 8)];
            acc[0] = __builtin_amdgcn_mfma_f32_32x32x16_bf16(a0, bfr, acc[0], 0, 0, 0);
            acc[1] = __builtin_amdgcn_mfma_f32_32x32x16_bf16(a1, bfr, acc[1], 0, 0, 0);
        }
    }

    // epilogue: bias + relu.  32x32 C/D: col=lane&31, row=(r&3)+8*(r>>2)+4*hl.
    const int gn = n0 + wc * 32 + nl;
    const float bv = bias[gn];
    #pragma unroll
    for (int mt = 0; mt < 2; ++mt) {
        #pragma unroll
        for (int r = 0; r < 16; ++r) {
            const int row32 = (r & 3) + 8 * (r >> 2) + 4 * hl;
            const int gm = m0 + wr * 64 + mt * 32 + row32;
            float v = acc[mt][r] + bv;
            out[(size_t)gm * N + gn] = v > 0.f ? v : 0.f;
        }
    }
}

// ---------------------------------------------------------------------------
extern "C" void kernel_launch(void* const* d_in, const int* in_sizes, int n_in,
                              void* d_out, int out_size, void* d_ws, size_t ws_size,
                              hipStream_t stream) {
    const float* h    = (const float*)d_in[0];   // (1, B, 64) f32
    const float* pos  = (const float*)d_in[2];   // (B, 2)     f32
    const float* W    = (const float*)d_in[4];   // (K, N)     f32
    const float* bias = (const float*)d_in[5];   // (N,)       f32

    const int B = in_sizes[0] / 64;       // 4096
    const int N = in_sizes[5];            // 1024
    const int K = 64 * 64;                // GRID^2 * H_DIM = 4096

    short* pooled = (short*)d_ws;                  // B*K bf16 = 32 MB
    short* Wt     = pooled + (size_t)B * K;        // N*K bf16 =  8 MB
    float* out    = (float*)d_out;

    const int poolBlocks = B / 4;                  // 1024
    const int castBlocks = (K / 64) * (N / 64);    // 1024
    prep_kernel<<<poolBlocks + castBlocks, 256, 0, stream>>>(
        h, pos, pooled, W, Wt, K, N, poolBlocks);
    gemm_bias_relu<<<(B / BM) * (N / BN), 256, 0, stream>>>(
        pooled, Wt, bias, out, B, N, K);
}

// Round 11
// 130.689 us; speedup vs baseline: 1.0065x; 1.0065x over previous
//
#include <hip/hip_runtime.h>

// ---------------------------------------------------------------------------
// SocialPooling: pooled = per-person 8x8-grid scatter-add of neighbor hiddens,
// out = relu(pooled @ W + b).  M=B=4096, K=4096, N=1024.
// R11 (FINAL = R9): GEMM: 128x64 tile, BK=128, single-buffer 2-barrier loop,
// 256B/16-slot XOR granule swizzle (0 conflicts), 32x32x16 MFMA, XCD
// m-clustered mapping, grid 512 = 2 blocks/CU.  Best of 7 structural
// variants; at ~89% of its LDS-pipe cycle bound (HIP-level plateau).
// Prep: merged pool (bitmask walk, 2 cells/pass, float2 dims) + W transpose.
// ---------------------------------------------------------------------------

#define BM 128
#define BN 64
#define BK 128   // shorts (bf16) per K-block

typedef short short8 __attribute__((ext_vector_type(8)));
typedef short short4v __attribute__((ext_vector_type(4)));
typedef float floatx16 __attribute__((ext_vector_type(16)));

__device__ inline short f2bf(float x) {
    union { float f; unsigned u; } v; v.f = x;
    unsigned r = v.u + 0x7fffu + ((v.u >> 16) & 1u);   // round-to-nearest-even
    return (short)(r >> 16);
}

__device__ inline void gload_lds16(const void* g, void* l) {
    __builtin_amdgcn_global_load_lds(
        (const __attribute__((address_space(1))) void*)g,
        (__attribute__((address_space(3))) void*)l,
        16, 0, 0);
}

// ---------------------------------------------------------------------------
// Kernel 1: prep = pool (blocks 0..1023) + W transpose/cast (blocks 1024..2047)
// merged so the two independent stages run concurrently.
// ---------------------------------------------------------------------------
__global__ __launch_bounds__(256) void prep_kernel(
    const float* __restrict__ h,     // (B, 64)
    const float* __restrict__ pos,   // (B, 2)
    short* __restrict__ pooled,      // (B, 4096) bf16
    const float* __restrict__ W,     // (K, N)
    short* __restrict__ Wt,          // (N, K) bf16
    int K, int N, int poolBlocks)
{
    __shared__ __align__(16) unsigned char sh[18944];
    const int tid = threadIdx.x;

    if ((int)blockIdx.x < poolBlocks) {
        // ----- pooling: 4 persons of one sequence per block -----
        float* hs = (float*)sh;                          // 64*64 f32 = 16 KB
        float* px = (float*)(sh + 16384);
        float* py = (float*)(sh + 16640);
        unsigned long long* wmask = (unsigned long long*)(sh + 16896); // 4*64

        const int lane = tid & 63;
        const int w    = tid >> 6;
        const int s    = blockIdx.x >> 4;
        const int grp  = blockIdx.x & 15;
        const size_t base = (size_t)s * 64;

        const float4* hv  = (const float4*)(h + base * 64);
        float4*       hsv = (float4*)hs;
        #pragma unroll
        for (int c = 0; c < 4; ++c) hsv[tid + c * 256] = hv[tid + c * 256];
        if (tid < 64) {
            float2 p = ((const float2*)pos)[base + tid];
            px[tid] = p.x; py[tid] = p.y;
        }
        wmask[w * 64 + lane] = 0ull;
        __syncthreads();

        const int i = grp * 4 + w;
        const float tlx = px[i] - 1.0f;
        const float tly = py[i] + 1.0f;
        const float brx = px[i] + 1.0f;
        const float bry = py[i] - 1.0f;

        {   // lane j: neighbor j's cell for person i (wave-local)
            const int j = lane;
            const float ox = px[j], oy = py[j];
            if (ox < brx && ox > tlx && oy < tly && oy > bry && j != i) {
                int cx = (int)floorf((ox - tlx) * 4.0f);
                int cy = (int)floorf((tly - oy) * 4.0f);
                atomicOr(&wmask[w * 64 + cx + cy * 8], 1ull << j);
            }
        }

        // phase C: 2 cells per wave-pass; lane half picks the cell, each lane
        // sums a float2 dim-pair.  fp32 math bit-identical to the reference.
        const int half = lane >> 5;            // cell offset 0/1
        const int d0   = (lane & 31) * 2;      // dim pair
        const size_t orow = (base + i) * 4096;
        unsigned short* pooledU = (unsigned short*)pooled;
        for (int c = 0; c < 64; c += 2) {
            unsigned long long m = wmask[w * 64 + c + half];
            float ax = 0.f, ay = 0.f;
            while (m) {
                int j0 = __builtin_ctzll(m); m &= m - 1;
                float2 hv2 = *(const float2*)&hs[j0 * 64 + d0];
                ax += hv2.x; ay += hv2.y;
            }
            unsigned pk = ((unsigned)(unsigned short)f2bf(ay) << 16)
                        |  (unsigned short)f2bf(ax);
            *(unsigned*)&pooledU[orow + (size_t)(c + half) * 64 + d0] = pk;
        }
    } else {
        // ----- W (K x N f32) -> Wt (N x K bf16), 64x64 tiles -----
        float* t = (float*)sh;                 // [64][65]
        const int bid = blockIdx.x - poolBlocks;
        const int k0 = (bid & 63) * 64;
        const int n0 = (bid >> 6) * 64;

        const int r  = tid >> 4;               // 0..15
        const int cq = (tid & 15) * 4;
        #pragma unroll
        for (int i2 = 0; i2 < 4; ++i2) {
            const int row = r + i2 * 16;
            float4 v = *(const float4*)&W[(size_t)(k0 + row) * N + n0 + cq];
            t[row * 65 + cq + 0] = v.x; t[row * 65 + cq + 1] = v.y;
            t[row * 65 + cq + 2] = v.z; t[row * 65 + cq + 3] = v.w;
        }
        __syncthreads();
        const int nl = tid >> 4;
        const int kq = (tid & 15) * 4;
        #pragma unroll
        for (int i2 = 0; i2 < 4; ++i2) {
            const int n = nl + i2 * 16;
            short4v o;
            o.x = f2bf(t[(kq + 0) * 65 + n]); o.y = f2bf(t[(kq + 1) * 65 + n]);
            o.z = f2bf(t[(kq + 2) * 65 + n]); o.w = f2bf(t[(kq + 3) * 65 + n]);
            *(short4v*)&Wt[(size_t)(n0 + n) * K + k0 + kq] = o;
        }
    }
}

// ---------------------------------------------------------------------------
// Kernel 2: C = relu(A @ Bt^T + bias).  A: MxK, Bt: NxK bf16.
// 128x64 block tile, BK=128, 4 waves (2x2), wave tile 64x32 = 2x1 of 32x32x16
// MFMA.  global_load_lds(16B) staging with XOR granule swizzle (0 conflicts
// measured).  XCD m-clustered block mapping (FETCH 135->49 MB measured).
// ---------------------------------------------------------------------------
__global__ __launch_bounds__(256) void gemm_bias_relu(
    const short* __restrict__ A,
    const short* __restrict__ Bt,
    const float* __restrict__ bias,
    float* __restrict__ out,
    int M, int N, int K)
{
    __shared__ __align__(16) short As[BM * BK];  // 32 KB
    __shared__ __align__(16) short Bs[BN * BK];  // 16 KB

    const int tid  = threadIdx.x;
    const int lane = tid & 63;
    const int wave = tid >> 6;
    const int wr = wave >> 1;          // wave row (m): 0..1
    const int wc = wave & 1;           // wave col (n): 0..1
    const int nl = lane & 31;          // MFMA row/col within 32
    const int hl = lane >> 5;          // K-half
    const int ml = lane & 15;          // swizzle key (= row&15)

    // XCD m-clustered mapping (dispatch: block b -> XCD b%8)
    const int b  = blockIdx.x;
    const int ib = b >> 3;
    const int m0 = ((b & 7) * 4 + (ib >> 4)) * BM;
    const int n0 = (ib & 15) * BN;

    const int r4   = lane >> 4;        // row within 4-row staging group
    const int slot = lane & 15;        // 16B-granule slot within 256B row

    const short* ag[8];
    const short* bg[4];
    #pragma unroll
    for (int c = 0; c < 8; ++c) {
        const int gi = c * 4 + wave;           // 0..31
        const int rl = gi * 4 + r4;            // 0..127
        ag[c] = A + (size_t)(m0 + rl) * K + (slot ^ (rl & 15)) * 8;
    }
    #pragma unroll
    for (int c = 0; c < 4; ++c) {
        const int gi = c * 4 + wave;           // 0..15
        const int rl = gi * 4 + r4;            // 0..63
        bg[c] = Bt + (size_t)(n0 + rl) * K + (slot ^ (rl & 15)) * 8;
    }

    floatx16 acc[2];
    #pragma unroll
    for (int mt = 0; mt < 2; ++mt)
        #pragma unroll
        for (int r = 0; r < 16; ++r) acc[mt][r] = 0.f;

    for (int kb = 0; kb < K; kb += BK) {
        if (kb) __syncthreads();
        #pragma unroll
        for (int c = 0; c < 8; ++c) {
            gload_lds16(ag[c], &As[(c * 4 + wave) * 512]);
            ag[c] += BK;
        }
        #pragma unroll
        for (int c = 0; c < 4; ++c) {
            gload_lds16(bg[c], &Bs[(c * 4 + wave) * 512]);
            bg[c] += BK;
        }
        __syncthreads();

        #pragma unroll
        for (int t = 0; t < 8; ++t) {                  // 8 x K=16 steps
            const int g  = 2 * t + hl;                 // needed granule
            short8 a0 = *(const short8*)&As[(wr * 64 +      nl) * BK + ((g ^ ml) * 8)];
            short8 a1 = *(const short8*)&As[(wr * 64 + 32 + nl) * BK + ((g ^ ml) * 8)];
            short8 bfr = *(const short8*)&Bs[(wc * 32 +     nl) * BK + ((g ^ ml) * 8)];
            acc[0] = __builtin_amdgcn_mfma_f32_32x32x16_bf16(a0, bfr, acc[0], 0, 0, 0);
            acc[1] = __builtin_amdgcn_mfma_f32_32x32x16_bf16(a1, bfr, acc[1], 0, 0, 0);
        }
    }

    // epilogue: bias + relu.  32x32 C/D: col=lane&31, row=(r&3)+8*(r>>2)+4*hl.
    const int gn = n0 + wc * 32 + nl;
    const float bv = bias[gn];
    #pragma unroll
    for (int mt = 0; mt < 2; ++mt) {
        #pragma unroll
        for (int r = 0; r < 16; ++r) {
            const int row32 = (r & 3) + 8 * (r >> 2) + 4 * hl;
            const int gm = m0 + wr * 64 + mt * 32 + row32;
            float v = acc[mt][r] + bv;
            out[(size_t)gm * N + gn] = v > 0.f ? v : 0.f;
        }
    }
}

// ---------------------------------------------------------------------------
extern "C" void kernel_launch(void* const* d_in, const int* in_sizes, int n_in,
                              void* d_out, int out_size, void* d_ws, size_t ws_size,
                              hipStream_t stream) {
    const float* h    = (const float*)d_in[0];   // (1, B, 64) f32
    const float* pos  = (const float*)d_in[2];   // (B, 2)     f32
    const float* W    = (const float*)d_in[4];   // (K, N)     f32
    const float* bias = (const float*)d_in[5];   // (N,)       f32

    const int B = in_sizes[0] / 64;       // 4096
    const int N = in_sizes[5];            // 1024
    const int K = 64 * 64;                // GRID^2 * H_DIM = 4096

    short* pooled = (short*)d_ws;                  // B*K bf16 = 32 MB
    short* Wt     = pooled + (size_t)B * K;        // N*K bf16 =  8 MB
    float* out    = (float*)d_out;

    const int poolBlocks = B / 4;                  // 1024
    const int castBlocks = (K / 64) * (N / 64);    // 1024
    prep_kernel<<<poolBlocks + castBlocks, 256, 0, stream>>>(
        h, pos, pooled, W, Wt, K, N, poolBlocks);
    gemm_bias_relu<<<(B / BM) * (N / BN), 256, 0, stream>>>(
        pooled, Wt, bias, out, B, N, K);
}